// Round 6
// baseline (205.523 us; speedup 1.0000x reference)
//
#include <hip/hip_runtime.h>
#include <hip/hip_bf16.h>
#include <cstdint>

#define NCAMS 6
#define NQ 2500
#define EMBED 256
#define HEADS 8
#define DHEAD 32
#define LTOT 19560
#define MVAL (NCAMS * LTOT) /* 117360 */

typedef __attribute__((ext_vector_type(8))) short bf16x8;
typedef __attribute__((ext_vector_type(4))) float f32x4;

__device__ __forceinline__ unsigned short f2bf(float f) {
  unsigned u = __float_as_uint(f);
  return (unsigned short)((u + 0x7fffu + ((u >> 16) & 1u)) >> 16);
}
__device__ __forceinline__ unsigned short bfbits(float x) {
  __hip_bfloat16 h = __float2bfloat16(x);
  return __builtin_bit_cast(unsigned short, h);
}

// ---------------------------------------------------------------------------
// Kernel P: all weight transposes -> bf16, plus query -> bf16.
// ---------------------------------------------------------------------------
__global__ __launch_bounds__(256) void k_prep(
    const float* __restrict__ Wv, const float* __restrict__ Woff,
    const float* __restrict__ Wattn, const float* __restrict__ Wout,
    const float* __restrict__ query,
    unsigned short* __restrict__ WT, unsigned short* __restrict__ WTq,
    unsigned short* __restrict__ WoutT, unsigned short* __restrict__ qbf)
{
  const int b = blockIdx.x, t = threadIdx.x;
  if (b < 256) {
    WT[(size_t)b * 256 + t] = f2bf(Wv[(size_t)t * 256 + b]);
  } else if (b < 768) {
    int c = b - 256;
    WTq[(size_t)c * 256 + t] = f2bf(Woff[(size_t)t * 512 + c]);
  } else if (b < 1024) {
    int c = b - 768;
    WTq[(size_t)(512 + c) * 256 + t] = f2bf(Wattn[(size_t)t * 256 + c]);
  } else if (b < 1280) {
    int c = b - 1024;
    WoutT[(size_t)c * 256 + t] = f2bf(Wout[(size_t)t * 256 + c]);
  } else {
    int q = b - 1280;
    qbf[(size_t)q * 256 + t] = f2bf(query[(size_t)q * 256 + t]);
  }
}

// ---------------------------------------------------------------------------
// Kernel A (v2): val = bf16( key_feats @ W_value + b_value )
// Barrier-free main loop: each wave owns a 64x64 output tile; MFMA fragments
// loaded DIRECTLY from global (A: f32->bf16 in-reg; B: WT bf16, L2-resident).
// Epilogue: per-wave LDS transpose -> coalesced dwordx4 stores.
// 256 threads = 4 waves; wave w covers cols w*64..w*64+63; grid = rows/64.
// ---------------------------------------------------------------------------
__global__ __launch_bounds__(256, 2) void k_valproj(
    const float* __restrict__ A,            // (117360, 256) f32
    const unsigned short* __restrict__ WT,  // (256 cols, 256 k) bf16
    const float* __restrict__ bv,           // (256,)
    unsigned short* __restrict__ val)       // (117360, 256) bf16
{
  __shared__ unsigned short tl[4][64][72];  // padded: conflict-light epilogue
  const int t = threadIdx.x;
  const int lane = t & 63;
  const int w = t >> 6;
  const int laneM = lane & 15, kGrp = lane >> 4;
  const int bm = blockIdx.x * 64;
  const int col0 = w * 64;

  int arow[4];
#pragma unroll
  for (int m = 0; m < 4; ++m) arow[m] = min(bm + m * 16 + laneM, MVAL - 1);

  f32x4 acc[4][4];
#pragma unroll
  for (int m = 0; m < 4; ++m)
#pragma unroll
    for (int n = 0; n < 4; ++n) acc[m][n] = {0.f, 0.f, 0.f, 0.f};

#pragma unroll 4
  for (int kk = 0; kk < 8; ++kk) {
    const int k0 = kk * 32 + kGrp * 8;
    bf16x8 af[4], bfr[4];
#pragma unroll
    for (int n = 0; n < 4; ++n)
      bfr[n] = *(const bf16x8*)&WT[(size_t)(col0 + n * 16 + laneM) * 256 + k0];
#pragma unroll
    for (int m = 0; m < 4; ++m) {
      const float* ap = &A[(size_t)arow[m] * 256 + k0];
      float4 x = *(const float4*)ap;
      float4 y = *(const float4*)(ap + 4);
      union { bf16x8 v; unsigned short u[8]; } c;
      c.u[0] = bfbits(x.x); c.u[1] = bfbits(x.y);
      c.u[2] = bfbits(x.z); c.u[3] = bfbits(x.w);
      c.u[4] = bfbits(y.x); c.u[5] = bfbits(y.y);
      c.u[6] = bfbits(y.z); c.u[7] = bfbits(y.w);
      af[m] = c.v;
    }
#pragma unroll
    for (int m = 0; m < 4; ++m)
#pragma unroll
      for (int n = 0; n < 4; ++n)
        acc[m][n] = __builtin_amdgcn_mfma_f32_16x16x32_bf16(af[m], bfr[n], acc[m][n], 0, 0, 0);
  }

  float bvn[4];
#pragma unroll
  for (int n = 0; n < 4; ++n) bvn[n] = bv[col0 + n * 16 + laneM];

#pragma unroll
  for (int m = 0; m < 4; ++m)
#pragma unroll
    for (int n = 0; n < 4; ++n)
#pragma unroll
      for (int r = 0; r < 4; ++r)
        tl[w][m * 16 + kGrp * 4 + r][n * 16 + laneM] = bfbits(acc[m][n][r] + bvn[n]);
  __syncthreads();

  const int r8 = lane >> 3, c8 = lane & 7;
#pragma unroll
  for (int i = 0; i < 8; ++i) {
    int rl = i * 8 + r8;
    int row = bm + rl;
    if (row < MVAL) {
      uint4 v = *(const uint4*)&tl[w][rl][c8 * 8];
      *(uint4*)&val[(size_t)row * 256 + col0 + c8 * 8] = v;
    }
  }
}

// ---------------------------------------------------------------------------
// Kernel G: generic small-M GEMM.  C(M,N) = A_bf16(M,256) @ BT_bf16(N,256)^T
//           + bias (split ba/bb at bsplit) [+ resid(M,256) if withResid]
// ---------------------------------------------------------------------------
__global__ __launch_bounds__(256, 2) void k_gemm_small(
    const unsigned short* __restrict__ A,
    const unsigned short* __restrict__ BT,
    const float* __restrict__ ba, const float* __restrict__ bb, int bsplit,
    const float* __restrict__ resid,
    float* __restrict__ C, int M, int N, int withResid)
{
  __shared__ unsigned short As[128 * 64];
  __shared__ unsigned short Bs[128 * 64];
  const int t = threadIdx.x;
  const int lane = t & 63;
  const int wid = t >> 6;
  const int wm = wid >> 1, wn = wid & 1;
  const int laneM = lane & 15, kGrp = lane >> 4;
  const int bm = blockIdx.x * 128;
  const int bn = blockIdx.y * 128;

  const int aC = t & 7, aR0 = t >> 3;

  uint4 aRegs[2][4];
  uint4 bRegs[2][4];
  f32x4 acc[4][4];
#pragma unroll
  for (int m = 0; m < 4; ++m)
#pragma unroll
    for (int n = 0; n < 4; ++n) acc[m][n] = {0.f, 0.f, 0.f, 0.f};

#pragma unroll
  for (int p = 0; p < 4; ++p) {
    int arow = bm + aR0 + p * 32;
    aRegs[0][p] = (arow < M) ? *(const uint4*)&A[(size_t)arow * 256 + aC * 8]
                             : make_uint4(0u, 0u, 0u, 0u);
    bRegs[0][p] = *(const uint4*)&BT[(size_t)(bn + aR0 + p * 32) * 256 + aC * 8];
  }

#pragma unroll
  for (int kk = 0; kk < 4; ++kk) {
    const int cur = kk & 1, nxt = cur ^ 1;
    if (kk) __syncthreads();
#pragma unroll
    for (int p = 0; p < 4; ++p) {
      int row = aR0 + p * 32;
      int elem = row * 64 + ((aC ^ (row & 7)) << 3);
      *(uint4*)&As[elem] = aRegs[cur][p];
      *(uint4*)&Bs[elem] = bRegs[cur][p];
    }
    __syncthreads();
    if (kk < 3) {
      const int kn = (kk + 1) * 64;
#pragma unroll
      for (int p = 0; p < 4; ++p) {
        int arow = bm + aR0 + p * 32;
        aRegs[nxt][p] = (arow < M)
            ? *(const uint4*)&A[(size_t)arow * 256 + kn + aC * 8]
            : make_uint4(0u, 0u, 0u, 0u);
        bRegs[nxt][p] = *(const uint4*)&BT[(size_t)(bn + aR0 + p * 32) * 256 + kn + aC * 8];
      }
    }
#pragma unroll
    for (int ks = 0; ks < 2; ++ks) {
      bf16x8 af[4], bfr[4];
#pragma unroll
      for (int m = 0; m < 4; ++m) {
        int row = wm * 64 + m * 16 + laneM;
        af[m] = *(bf16x8*)&As[row * 64 + (((ks * 4 + kGrp) ^ (row & 7)) << 3)];
      }
#pragma unroll
      for (int n = 0; n < 4; ++n) {
        int row = wn * 64 + n * 16 + laneM;
        bfr[n] = *(bf16x8*)&Bs[row * 64 + (((ks * 4 + kGrp) ^ (row & 7)) << 3)];
      }
#pragma unroll
      for (int m = 0; m < 4; ++m)
#pragma unroll
        for (int n = 0; n < 4; ++n)
          acc[m][n] = __builtin_amdgcn_mfma_f32_16x16x32_bf16(af[m], bfr[n], acc[m][n], 0, 0, 0);
    }
  }

  float bvn[4];
#pragma unroll
  for (int n = 0; n < 4; ++n) {
    int col = bn + wn * 64 + n * 16 + laneM;
    bvn[n] = (col < bsplit) ? ba[col] : bb[col - bsplit];
  }
#pragma unroll
  for (int m = 0; m < 4; ++m) {
#pragma unroll
    for (int r = 0; r < 4; ++r) {
      int row = bm + wm * 64 + m * 16 + kGrp * 4 + r;
      if (row < M) {
#pragma unroll
        for (int n = 0; n < 4; ++n) {
          int col = bn + wn * 64 + n * 16 + laneM;
          float v = acc[m][n][r] + bvn[n];
          if (withResid) v += resid[(size_t)row * 256 + col];
          C[(size_t)row * N + col] = v;
        }
      }
    }
  }
}

// ---------------------------------------------------------------------------
// Kernel M: bev_mask -> valid[6*2500], on-device dtype detect (int32 vs u8).
// ---------------------------------------------------------------------------
__global__ __launch_bounds__(256) void k_maskvalid(
    const unsigned char* __restrict__ MSK,
    unsigned char* __restrict__ valid)
{
  __shared__ int s_u8;
  const int t = threadIdx.x;
  if (t == 0) s_u8 = 0;
  __syncthreads();
  if ((t & 3) && MSK[t]) atomicOr(&s_u8, 1);
  __syncthreads();
  const int isU8 = s_u8;

  const int i = blockIdx.x * 256 + t;
  if (i < NCAMS * NQ) {
    int any;
    if (isU8) {
      const unsigned char* p = MSK + (size_t)i * 4;
      any = p[0] | p[1] | p[2] | p[3];
    } else {
      const int* p = (const int*)MSK + (size_t)i * 4;
      any = p[0] | p[1] | p[2] | p[3];
    }
    valid[i] = any ? 1 : 0;
  }
}

// ---------------------------------------------------------------------------
// Kernel C (two-phase sampling).  OFFLOG row = [OFF(512) | LOG(256)].
// ---------------------------------------------------------------------------
__global__ __launch_bounds__(256) void k_sample(
    const unsigned short* __restrict__ val,   // (117360, 256) bf16
    const float* __restrict__ OFFLOG,         // (2500, 768)
    const float* __restrict__ REF,            // (6,1,2500,4,2)
    const unsigned char* __restrict__ valid,  // (6,2500)
    unsigned short* __restrict__ slots)       // (2500,256) bf16
{
  __shared__ int2  s_pack[4][NCAMS][256];
  __shared__ float s_off[512];
  __shared__ float s_ref[48];
  __shared__ int   s_valid[6];

  const int q = blockIdx.x;
  const int t = threadIdx.x;

  s_off[t]       = OFFLOG[(size_t)q * 768 + t];
  s_off[t + 256] = OFFLOG[(size_t)q * 768 + 256 + t];
  if (t < 48) s_ref[t] = REF[(size_t)(t >> 3) * (NQ * 8) + (size_t)q * 8 + (t & 7)];
  if (t < 6) s_valid[t] = valid[(size_t)t * NQ + q];

  float logit = OFFLOG[(size_t)q * 768 + 512 + t];
  float m = logit;
#pragma unroll
  for (int o = 16; o > 0; o >>= 1) m = fmaxf(m, __shfl_xor(m, o, 32));
  float e = __expf(logit - m);
  float s = e;
#pragma unroll
  for (int o = 16; o > 0; o >>= 1) s += __shfl_xor(s, o, 32);
  const float a = e / s;
  __syncthreads();

  {
    const int h1 = t >> 5, lp = t & 31, lvl = lp >> 3, p = lp & 7, z = p & 3;
    const int WW = 160 >> lvl;
    const int HH = (lvl < 3) ? (92 >> lvl) : 12;
    const int S  = (lvl == 0) ? 0 : (lvl == 1) ? 14720 : (lvl == 2) ? 18400 : 19320;
    const float Wf = (float)WW, Hf = (float)HH;
    const float ox = s_off[h1 * 64 + lp * 2];
    const float oy = s_off[h1 * 64 + lp * 2 + 1];
#pragma unroll 1
    for (int cam = 0; cam < NCAMS; ++cam) {
      if (!s_valid[cam]) continue;
      float rx = s_ref[cam * 8 + z * 2];
      float ry = s_ref[cam * 8 + z * 2 + 1];
      float x = rx * Wf + ox - 0.5f;
      float y = ry * Hf + oy - 0.5f;
      float x0f = floorf(x), y0f = floorf(y);
      float fx = x - x0f, fy = y - y0f;
      int x0 = (int)x0f, y0 = (int)y0f;
      int base = cam * LTOT + S;
#pragma unroll
      for (int dy = 0; dy < 2; ++dy) {
        int yi = y0 + dy;
        float wy = dy ? fy : 1.f - fy;
        int yc = min(max(yi, 0), HH - 1);
        bool vy = (yi >= 0) && (yi < HH);
#pragma unroll
        for (int dx = 0; dx < 2; ++dx) {
          int xi = x0 + dx;
          float wx = dx ? fx : 1.f - fx;
          int xc = min(max(xi, 0), WW - 1);
          bool vv = vy && (xi >= 0) && (xi < WW);
          float wgt = vv ? wx * wy * a : 0.f;
          int addr = (base + yc * WW + xc) * 512;
          s_pack[dy * 2 + dx][cam][t] = make_int2(addr, __float_as_int(wgt));
        }
      }
    }
  }
  __syncthreads();

  const int h = t >> 5, pp = (t >> 3) & 3, l8 = t & 7;
  const unsigned dconst = (unsigned)(h * 64 + l8 * 8);
  const char* vb = (const char*)val;
  int nvalid = s_valid[0] + s_valid[1] + s_valid[2] + s_valid[3] + s_valid[4] + s_valid[5];
  float inv = 1.f / fmaxf((float)nvalid, 1.f);

  f32x4 acc = {0.f, 0.f, 0.f, 0.f};
#pragma unroll 1
  for (int cam = 0; cam < NCAMS; ++cam) {
    if (!s_valid[cam]) continue;
#pragma unroll
    for (int it = 0; it < 8; ++it) {
      const int idx = h * 32 + pp + it * 4;
      int2 pk0 = s_pack[0][cam][idx];
      int2 pk1 = s_pack[1][cam][idx];
      int2 pk2 = s_pack[2][cam][idx];
      int2 pk3 = s_pack[3][cam][idx];
      uint2 v0 = *(const uint2*)(vb + (size_t)((unsigned)pk0.x + dconst));
      uint2 v1 = *(const uint2*)(vb + (size_t)((unsigned)pk1.x + dconst));
      uint2 v2 = *(const uint2*)(vb + (size_t)((unsigned)pk2.x + dconst));
      uint2 v3 = *(const uint2*)(vb + (size_t)((unsigned)pk3.x + dconst));
      float w0 = __int_as_float(pk0.y), w1 = __int_as_float(pk1.y);
      float w2 = __int_as_float(pk2.y), w3 = __int_as_float(pk3.y);
      acc[0] += w0 * __uint_as_float(v0.x << 16);
      acc[1] += w0 * __uint_as_float(v0.x & 0xffff0000u);
      acc[2] += w0 * __uint_as_float(v0.y << 16);
      acc[3] += w0 * __uint_as_float(v0.y & 0xffff0000u);
      acc[0] += w1 * __uint_as_float(v1.x << 16);
      acc[1] += w1 * __uint_as_float(v1.x & 0xffff0000u);
      acc[2] += w1 * __uint_as_float(v1.y << 16);
      acc[3] += w1 * __uint_as_float(v1.y & 0xffff0000u);
      acc[0] += w2 * __uint_as_float(v2.x << 16);
      acc[1] += w2 * __uint_as_float(v2.x & 0xffff0000u);
      acc[2] += w2 * __uint_as_float(v2.y << 16);
      acc[3] += w2 * __uint_as_float(v2.y & 0xffff0000u);
      acc[0] += w3 * __uint_as_float(v3.x << 16);
      acc[1] += w3 * __uint_as_float(v3.x & 0xffff0000u);
      acc[2] += w3 * __uint_as_float(v3.y << 16);
      acc[3] += w3 * __uint_as_float(v3.y & 0xffff0000u);
    }
  }

#pragma unroll
  for (int i = 0; i < 4; ++i) {
    acc[i] += __shfl_xor(acc[i], 8);
    acc[i] += __shfl_xor(acc[i], 16);
  }
  if (pp == 0) {
    uint2 r;
    r.x = (unsigned)f2bf(acc[0] * inv) | ((unsigned)f2bf(acc[1] * inv) << 16);
    r.y = (unsigned)f2bf(acc[2] * inv) | ((unsigned)f2bf(acc[3] * inv) << 16);
    *(uint2*)&slots[(size_t)q * 256 + h * 32 + l8 * 4] = r;
  }
}

// ---------------------------------------------------------------------------
extern "C" void kernel_launch(void* const* d_in, const int* in_sizes, int n_in,
                              void* d_out, int out_size, void* d_ws, size_t ws_size,
                              hipStream_t stream) {
  const float* query     = (const float*)d_in[0];
  const float* key_feats = (const float*)d_in[1];
  const float* ref       = (const float*)d_in[2];
  const unsigned char* mask = (const unsigned char*)d_in[3];
  // d_in[4] = spatial_shapes (compile-time constants)
  const float* Wv    = (const float*)d_in[5];
  const float* bv    = (const float*)d_in[6];
  const float* Woff  = (const float*)d_in[7];
  const float* boff  = (const float*)d_in[8];
  const float* Wattn = (const float*)d_in[9];
  const float* battn = (const float*)d_in[10];
  const float* Wout  = (const float*)d_in[11];
  const float* bout  = (const float*)d_in[12];
  float* out = (float*)d_out;

  char* ws = (char*)d_ws;
  size_t off = 0;
  unsigned short* val   = (unsigned short*)(ws + off); off += (size_t)MVAL * 256 * 2;
  unsigned short* WT    = (unsigned short*)(ws + off); off += 256 * 256 * 2;
  unsigned short* WTq   = (unsigned short*)(ws + off); off += 768 * 256 * 2;
  unsigned short* WoutT = (unsigned short*)(ws + off); off += 256 * 256 * 2;
  unsigned short* qbf   = (unsigned short*)(ws + off); off += (size_t)NQ * 256 * 2;
  float* OFFLOG = (float*)(ws + off); off += (size_t)NQ * 768 * 4;
  unsigned short* slots = (unsigned short*)(ws + off); off += (size_t)NQ * 256 * 2;
  unsigned char* valid  = (unsigned char*)(ws + off); off += NCAMS * NQ;

  hipLaunchKernelGGL(k_prep, dim3(1280 + NQ), dim3(256), 0, stream,
                     Wv, Woff, Wattn, Wout, query, WT, WTq, WoutT, qbf);
  hipLaunchKernelGGL(k_valproj, dim3((MVAL + 63) / 64), dim3(256), 0, stream,
                     key_feats, WT, bv, val);
  hipLaunchKernelGGL(k_gemm_small, dim3((NQ + 127) / 128, 6), dim3(256), 0, stream,
                     qbf, WTq, boff, battn, 512, (const float*)nullptr, OFFLOG, NQ, 768, 0);
  hipLaunchKernelGGL(k_maskvalid, dim3((NCAMS * NQ + 255) / 256), dim3(256), 0, stream,
                     mask, valid);
  hipLaunchKernelGGL(k_sample, dim3(NQ), dim3(256), 0, stream,
                     val, OFFLOG, ref, valid, slots);
  hipLaunchKernelGGL(k_gemm_small, dim3((NQ + 127) / 128, 2), dim3(256), 0, stream,
                     slots, WoutT, bout, bout, 1 << 30, query, out, NQ, 256, 1);
}